// Round 5
// baseline (1988.755 us; speedup 1.0000x reference)
//
#include <hip/hip_runtime.h>
#include <cstdint>
#include <cstddef>

// NCA: x = bilinear(seed)->1024x1024 NHWC fp32; 64x [conv3x3(8->32)+gelu, conv1x1(32->8)*0.1,
// masked add]; project 8->1. Convs via mfma_f32_16x16x32_f16 implicit GEMM.
// conv3x3 K-order: k = tap*8 + c  (A-frag = one tap's 8 channels = ds_read_b128)
// conv1x1 K-order: k' = 2c + b, channel = c + 16b (so gelu pair (m, m+16) packs into one b32)
// gelu: exact erf via A&S 7.1.26 branchless (|err|<=1.5e-7), no libm.
// PRNG: jax threefry2x32 partitionable: subkey[i]=raw pair tf2x32((0,42),(0,i));
// bits[p]=o0^o1 of tf2x32(subkey,(0,p)); mask = (bits>>9) > 2^22.

#define HH 1024
#define WW 1024
#define SD 8
#define HID 32
#define TX 32
#define TY 16

typedef _Float16 f16x8 __attribute__((ext_vector_type(8)));
typedef float f32x4 __attribute__((ext_vector_type(4)));

__host__ __device__ inline uint32_t rotl32(uint32_t x, int n) {
  return (x << n) | (x >> (32 - n));
}

__host__ __device__ inline void tf2x32(uint32_t k0, uint32_t k1,
                                       uint32_t x0, uint32_t x1,
                                       uint32_t& o0, uint32_t& o1) {
  uint32_t ks0 = k0, ks1 = k1, ks2 = k0 ^ k1 ^ 0x1BD11BDAu;
  x0 += ks0; x1 += ks1;
#define TFR(r) { x0 += x1; x1 = rotl32(x1, (r)); x1 ^= x0; }
  TFR(13) TFR(15) TFR(26) TFR(6)  x0 += ks1; x1 += ks2 + 1u;
  TFR(17) TFR(29) TFR(16) TFR(24) x0 += ks2; x1 += ks0 + 2u;
  TFR(13) TFR(15) TFR(26) TFR(6)  x0 += ks0; x1 += ks1 + 3u;
  TFR(17) TFR(29) TFR(16) TFR(24) x0 += ks1; x1 += ks2 + 4u;
  TFR(13) TFR(15) TFR(26) TFR(6)  x0 += ks2; x1 += ks0 + 5u;
#undef TFR
  o0 = x0; o1 = x1;
}

// gelu(x) = 0.5x(1+erf(x/sqrt2)) = 0.5x + 0.5|x|*erf(|x|/sqrt2)
// erf via A&S 7.1.26, branchless, |err| <= 1.5e-7.
__device__ inline float gelu_fast(float x) {
  const float ax = __builtin_fabsf(x);
  const float ay = 0.70710678118654752f * ax;
  const float t = __builtin_amdgcn_rcpf(fmaf(0.3275911f, ay, 1.0f));
  float p = fmaf(1.061405429f, t, -1.453152027f);
  p = fmaf(p, t, 1.421413741f);
  p = fmaf(p, t, -0.284496736f);
  p = fmaf(p, t, 0.254829592f);
  p *= t;
  const float e = __expf(-ay * ay);           // v_mul + v_exp_f32
  const float erfv = fmaf(-p, e, 1.0f);       // erf(|x|/sqrt2)
  return fmaf(0.5f * ax, erfv, 0.5f * x);
}

// ---- bilinear upsample 8x8 -> 1024x1024, NHWC fp32 out ----
__global__ void init_kernel(const float* __restrict__ seed, float* __restrict__ dst) {
  int p = blockIdx.x * blockDim.x + threadIdx.x;
  if (p >= HH * WW) return;
  int y = p >> 10, x = p & 1023;
  float fy = (y + 0.5f) * (8.0f / HH) - 0.5f;
  float fx = (x + 0.5f) * (8.0f / WW) - 0.5f;
  int y0 = (int)floorf(fy); float wy = fy - (float)y0;
  int x0 = (int)floorf(fx); float wx = fx - (float)x0;
  int y0c = min(max(y0, 0), 7), y1c = min(max(y0 + 1, 0), 7);
  int x0c = min(max(x0, 0), 7), x1c = min(max(x0 + 1, 0), 7);
  float vals[8];
#pragma unroll
  for (int c = 0; c < SD; ++c) {
    const float* s = seed + c * 64;
    float v00 = s[y0c * 8 + x0c], v01 = s[y0c * 8 + x1c];
    float v10 = s[y1c * 8 + x0c], v11 = s[y1c * 8 + x1c];
    float v0 = v00 + (v01 - v00) * wx;
    float v1 = v10 + (v11 - v10) * wx;
    vals[c] = v0 + (v1 - v0) * wy;
  }
  f32x4 lo = {vals[0], vals[1], vals[2], vals[3]};
  f32x4 hi = {vals[4], vals[5], vals[6], vals[7]};
  *(f32x4*)(dst + (size_t)p * 8) = lo;
  *(f32x4*)(dst + (size_t)p * 8 + 4) = hi;
}

// ---- pack W1/W2 into MFMA B-fragment order ----
// W1f: n = nt*16+(lane&15), k = kc*32+(lane>>4)*8+j, k=tap*8+c -> tap=kc*4+(lane>>4), c=j
// W2f: n = lane&15, k' = (lane>>4)*8+j, channel = (k'>>1) + ((k'&1)<<4)
__global__ void prep_kernel(const float* __restrict__ W1, const float* __restrict__ W2,
                            _Float16* __restrict__ w1f, _Float16* __restrict__ w2f) {
  int tid = threadIdx.x;
  for (int i = tid; i < 2 * 3 * 64; i += 256) {
    int nt = i / 192, rem = i % 192;
    int kc = rem / 64, lane = rem % 64;
    int n = nt * 16 + (lane & 15);
    int tap = kc * 4 + (lane >> 4);
#pragma unroll
    for (int j = 0; j < 8; ++j) {
      float v = (tap < 9) ? W1[(n * SD + j) * 9 + tap] : 0.0f;
      w1f[i * 8 + j] = (_Float16)v;
    }
  }
  if (tid < 64) {
    int n = tid & 15;
#pragma unroll
    for (int j = 0; j < 8; ++j) {
      int kp = (tid >> 4) * 8 + j;
      int ch = (kp >> 1) + ((kp & 1) << 4);
      float v = (n < 8) ? W2[n * HID + ch] : 0.0f;
      w2f[tid * 8 + j] = (_Float16)v;
    }
  }
}

// ---- fused NCA step, MFMA implicit GEMM ----
__global__ __launch_bounds__(256) void step_kernel(
    const float* __restrict__ src, float* __restrict__ dst,
    const _Float16* __restrict__ w1f, const _Float16* __restrict__ w2f,
    const float* __restrict__ b1, const float* __restrict__ b2,
    uint32_t key0, uint32_t key1) {
  __shared__ _Float16 tile[(TY + 2) * (TX + 2) * SD];   // NHWC f16, halo +1
  __shared__ uint32_t hbuf[4][16 * 20];                 // per-wave h, pixel-major, packed pairs
  __shared__ float dxbuf[SD * 516];                     // SoA dx

  const int tid = threadIdx.x;
  const int bx = blockIdx.x, by = blockIdx.y;

  // ---- stage fp32 NHWC -> f16 NHWC LDS tile (zero pad outside) ----
  for (int i = tid; i < (TY + 2) * (TX + 2); i += 256) {
    int ly = i / (TX + 2), lx = i % (TX + 2);
    int gy = by * TY + ly - 1, gx = bx * TX + lx - 1;
    f16x8 v;
#pragma unroll
    for (int j = 0; j < 8; ++j) v[j] = (_Float16)0.0f;
    if ((unsigned)gy < HH && (unsigned)gx < WW) {
      const float* xp = src + (size_t)(gy * WW + gx) * 8;
      f32x4 lo = *(const f32x4*)xp;
      f32x4 hi = *(const f32x4*)(xp + 4);
#pragma unroll
      for (int j = 0; j < 4; ++j) { v[j] = (_Float16)lo[j]; v[4 + j] = (_Float16)hi[j]; }
    }
    *(f16x8*)&tile[i * 8] = v;
  }

  // ---- threefry masks for this thread's 2 update pixels (overlaps staging latency) ----
  float maskf[2];
#pragma unroll
  for (int it = 0; it < 2; ++it) {
    const int pl = it * 256 + tid;
    const uint32_t gp = (uint32_t)((by * TY + (pl >> 5)) * WW + bx * TX + (pl & 31));
    uint32_t r0, r1;
    tf2x32(key0, key1, 0u, gp, r0, r1);
    maskf[it] = (((r0 ^ r1) >> 9) > 0x400000u) ? 1.0f : 0.0f;
  }
  __syncthreads();

  const int lane = tid & 63, w = tid >> 6;
  const int m = lane & 15, q = lane >> 4;

  // B fragments in VGPRs for the whole kernel
  f16x8 bf[2][3];
#pragma unroll
  for (int nt = 0; nt < 2; ++nt)
#pragma unroll
    for (int kc = 0; kc < 3; ++kc)
      bf[nt][kc] = *(const f16x8*)(w1f + ((nt * 3 + kc) * 64 + lane) * 8);
  f16x8 w2fr = *(const f16x8*)(w2f + lane * 8);
  const float b1v0 = b1[m], b1v1 = b1[m + 16];
  const float b2v = b2[m & 7];

  // per-lane A base pointers for the 3 K-chunks (taps 9..11 have B=0; clamp addr)
  const _Float16* ap[3];
#pragma unroll
  for (int kc = 0; kc < 3; ++kc) {
    int t = kc * 4 + q; if (t > 8) t = 0;
    ap[kc] = &tile[((t / 3) * (TX + 2) + m + (t % 3)) * 8];
  }

  uint32_t* hb = &hbuf[w][0];

#pragma unroll
  for (int r4 = 0; r4 < 4; ++r4) {
    const int y = w * 4 + r4;  // local row 0..15 (w uniform per wave)
#pragma unroll
    for (int xh = 0; xh < 2; ++xh) {
      const int x0 = xh * 16;
      f32x4 acc0 = {0.f, 0.f, 0.f, 0.f}, acc1 = {0.f, 0.f, 0.f, 0.f};
#pragma unroll
      for (int kc = 0; kc < 3; ++kc) {
        const f16x8 a = *(const f16x8*)(ap[kc] + (y * (TX + 2) + x0) * 8);
        acc0 = __builtin_amdgcn_mfma_f32_16x16x32_f16(a, bf[0][kc], acc0, 0, 0, 0);
        acc1 = __builtin_amdgcn_mfma_f32_16x16x32_f16(a, bf[1][kc], acc1, 0, 0, 0);
      }
      // gelu + packed transpose: pair (ch m, ch m+16) of pixel q*4+r -> one b32
#pragma unroll
      for (int r = 0; r < 4; ++r) {
        float h0 = gelu_fast(acc0[r] + b1v0);
        float h1 = gelu_fast(acc1[r] + b1v1);
        auto pk = __builtin_amdgcn_cvt_pkrtz(h0, h1);   // __fp16 ext_vector(2)
        hb[(q * 4 + r) * 20 + m] = __builtin_bit_cast(uint32_t, pk);
      }
      // conv1x1: A2[pixel m][k'=q*8+j]; dwords q*4..q*4+3 of row m (16B aligned: 20%4==0)
      const f16x8 a2 = *(const f16x8*)&hb[m * 20 + q * 4];
      f32x4 acc2 = {0.f, 0.f, 0.f, 0.f};
      acc2 = __builtin_amdgcn_mfma_f32_16x16x32_f16(a2, w2fr, acc2, 0, 0, 0);
      if (m < 8) {
        f32x4 dxv;
#pragma unroll
        for (int r = 0; r < 4; ++r) dxv[r] = (acc2[r] + b2v) * 0.1f;
        *(f32x4*)&dxbuf[m * 516 + y * TX + x0 + q * 4] = dxv;
      }
    }
  }
  __syncthreads();

  // ---- update: x_new = x + dx * mask (fp32 state path) ----
#pragma unroll
  for (int it = 0; it < 2; ++it) {
    const int pl = it * 256 + tid;
    const uint32_t gp = (uint32_t)((by * TY + (pl >> 5)) * WW + bx * TX + (pl & 31));
    const float mk = maskf[it];
    const float* xp = src + (size_t)gp * 8;
    f32x4 lo = *(const f32x4*)xp;
    f32x4 hi = *(const f32x4*)(xp + 4);
#pragma unroll
    for (int j = 0; j < 4; ++j) {
      lo[j] += dxbuf[j * 516 + pl] * mk;
      hi[j] += dxbuf[(4 + j) * 516 + pl] * mk;
    }
    float* op = dst + (size_t)gp * 8;
    *(f32x4*)op = lo;
    *(f32x4*)(op + 4) = hi;
  }
}

// ---- projection: out[p] = bp + sum_c x[p][c]*Wp[c] (NHWC) ----
__global__ void proj_kernel(const float* __restrict__ x,
                            const float* __restrict__ Wp,
                            const float* __restrict__ bp,
                            float* __restrict__ out) {
  int p = blockIdx.x * blockDim.x + threadIdx.x;
  if (p >= HH * WW) return;
  const float* xp = x + (size_t)p * 8;
  f32x4 lo = *(const f32x4*)xp;
  f32x4 hi = *(const f32x4*)(xp + 4);
  float acc = bp[0];
#pragma unroll
  for (int c = 0; c < 4; ++c) acc = fmaf(lo[c], Wp[c], acc);
#pragma unroll
  for (int c = 0; c < 4; ++c) acc = fmaf(hi[c], Wp[4 + c], acc);
  out[p] = acc;
}

extern "C" void kernel_launch(void* const* d_in, const int* in_sizes, int n_in,
                              void* d_out, int out_size, void* d_ws, size_t ws_size,
                              hipStream_t stream) {
  (void)in_sizes; (void)n_in; (void)out_size; (void)ws_size;
  const float* seed = (const float*)d_in[0];
  const float* W1   = (const float*)d_in[1];
  const float* b1   = (const float*)d_in[2];
  const float* W2   = (const float*)d_in[3];
  const float* b2   = (const float*)d_in[4];
  const float* Wp   = (const float*)d_in[5];
  const float* bp   = (const float*)d_in[6];
  float* out  = (float*)d_out;
  float* buf0 = (float*)d_ws;
  float* buf1 = buf0 + (size_t)SD * HH * WW;
  _Float16* w1f = (_Float16*)(buf1 + (size_t)SD * HH * WW);
  _Float16* w2f = w1f + 2 * 3 * 64 * 8;

  // 64 subkeys of jax.random.split(jax.random.key(42), 64) (raw pairs, no xor)
  uint32_t ka[64], kb[64];
  for (int i = 0; i < 64; ++i) tf2x32(0u, 42u, 0u, (uint32_t)i, ka[i], kb[i]);

  hipLaunchKernelGGL(prep_kernel, dim3(1), dim3(256), 0, stream, W1, W2, w1f, w2f);
  hipLaunchKernelGGL(init_kernel, dim3((HH * WW) / 256), dim3(256), 0, stream, seed, buf0);

  dim3 grid(WW / TX, HH / TY);
  float* s = buf0; float* d = buf1;
  for (int i = 0; i < 64; ++i) {
    hipLaunchKernelGGL(step_kernel, grid, dim3(256), 0, stream,
                       s, d, w1f, w2f, b1, b2, ka[i], kb[i]);
    float* t = s; s = d; d = t;
  }
  hipLaunchKernelGGL(proj_kernel, dim3((HH * WW) / 256), dim3(256), 0, stream,
                     s, Wp, bp, out);
}